// Round 10
// baseline (111.624 us; speedup 1.0000x reference)
//
#include <hip/hip_runtime.h>
#include <math.h>

#define N_ENT 20000
#define D 200
#define NB 8
#define NM 5
#define NBLK_MAIN 1250   // 16 entities per block

// ws layout (in floats)
#define Q_OFF     0        // 8 vec * 8 b * 200 = 12800
#define PART_OFF  12800    // 1250 blocks * 40 pairs * 4 = 200000
#define MNMX_OFF  212800   // 40 * 2 floats
#define STATD_OFF 212880   // 40 * 2 doubles = 160 floats
#define C_OFF     213040   // 40
#define CONST_OFF 213080   // 8
#define S_OFF     213088   // 5*8*20000 = 800000

#define COMP(v,j) ((j)==0 ? (v).x : (j)==1 ? (v).y : (j)==2 ? (v).z : (v).w)
#define LD4(p) (*(const float4*)(p))

// ---------------- K_q: build 8 per-b query vectors into ws ----------------
__global__ __launch_bounds__(256) void k_q(
    const int* __restrict__ batch, const float* __restrict__ eemb,
    const float* __restrict__ remb,
    const float* __restrict__ ce_re, const float* __restrict__ ce_im,
    const float* __restrict__ cr_re, const float* __restrict__ cr_im,
    const float* __restrict__ de, const float* __restrict__ dr,
    const float* __restrict__ ke, const float* __restrict__ kr,
    const float* __restrict__ se_h, const float* __restrict__ se_t,
    const float* __restrict__ sr, const float* __restrict__ sr_inv,
    float* __restrict__ ws)
{
    int b = blockIdx.x;
    int d = threadIdx.x;
    if (d >= D) return;
    int h = batch[b*48 + 0];
    int r = batch[b*48 + 2];
    float* q = ws + Q_OFF;

    float her = eemb[h*400 + d];
    float hei = eemb[h*400 + 200 + d];
    float ph  = remb[r*200 + d];
    float cph = cosf(ph), sph = sinf(ph);
    q[(0*8 + b)*200 + d] = her*cph - hei*sph;          // p_re
    q[(1*8 + b)*200 + d] = her*sph + hei*cph;          // p_im

    float cer = ce_re[h*200+d], cei = ce_im[h*200+d];
    float crr = cr_re[r*200+d], cri = cr_im[r*200+d];
    q[(2*8 + b)*200 + d] = cer*crr - cei*cri;          // s_re
    q[(3*8 + b)*200 + d] = cer*cri + cei*crr;          // s_im

    q[(4*8 + b)*200 + d] = ke[h*200+d] * kr[r*200+d];
    q[(5*8 + b)*200 + d] = de[h*200+d] * dr[r*200+d];
    q[(6*8 + b)*200 + d] = se_h[h*200+d] * sr[r*200+d];     // pairs with se_t[e]
    q[(7*8 + b)*200 + d] = se_t[h*200+d] * sr_inv[r*200+d]; // pairs with se_h[e]
}

// ---------------- K_main v10: no LDS, q from L1/L2, VGPR cap 128 (no spills) -------
// 256 threads = 4 waves. thread: bg = tid>>6 (wave, b-pair), ds = (tid>>3)&7 (d-quad),
// rg = tid&7 (e-pair). Register tile 2e x 2b, acc[5][2][2].
// q reads: per wave-instr one 128B L1 line (lanes vary ds only, rg broadcasts).
// E reads: 8 x 128B coalesced segments; 4 b-waves re-hit same lines in L1.
// Grid-limited occupancy ~4.9 waves/SIMD -> __launch_bounds__(256,4): VGPR<=128,
// fits the ~110-reg live set (v9's (256,6) forced 40 VGPR -> 17.7MB scratch spills).
__global__ __launch_bounds__(256, 4) void k_main(
    const float* __restrict__ eemb, const float* __restrict__ ce_re,
    const float* __restrict__ ce_im, const float* __restrict__ ke,
    const float* __restrict__ de, const float* __restrict__ se_h,
    const float* __restrict__ se_t, float* __restrict__ ws)
{
    const float* qg = ws + Q_OFF;
    float* S    = ws + S_OFF;
    float* part = ws + PART_OFF;

    const int tid = threadIdx.x;
    const int bg  = tid >> 6;        // wave = b-pair
    const int ds  = (tid >> 3) & 7;  // d-quad within 32-chunk
    const int rg  = tid & 7;         // e-pair
    const int e0  = blockIdx.x * 16;

    const int eA = e0 + 2*rg, eB = eA + 1;
    const int bA = 2*bg,      bB = bA + 1;

    float acc[NM][2][2];
#pragma unroll
    for (int m = 0; m < NM; ++m)
#pragma unroll
        for (int je = 0; je < 2; ++je)
#pragma unroll
            for (int jb = 0; jb < 2; ++jb) acc[m][je][jb] = 0.f;

    auto body = [&](int off) {
#define QLOAD(v, b)  LD4(qg + ((v)*8 + (b))*200 + off)
        { // rotate: q0 (p_re), q1 (p_im) vs t_re, t_im
            float4 q0A=QLOAD(0,bA), q0B=QLOAD(0,bB);
            float4 q1A=QLOAD(1,bA), q1B=QLOAD(1,bB);
            float4 t0A=LD4(eemb + (size_t)eA*400 + off);
            float4 t0B=LD4(eemb + (size_t)eB*400 + off);
            float4 t1A=LD4(eemb + (size_t)eA*400 + 200 + off);
            float4 t1B=LD4(eemb + (size_t)eB*400 + 200 + off);
#pragma unroll
            for (int k = 0; k < 4; ++k) {
                float dr_, di_;
                dr_=COMP(q0A,k)-COMP(t0A,k); di_=COMP(q1A,k)-COMP(t1A,k);
                acc[0][0][0] += __builtin_amdgcn_sqrtf(fmaf(dr_,dr_,di_*di_));
                dr_=COMP(q0B,k)-COMP(t0A,k); di_=COMP(q1B,k)-COMP(t1A,k);
                acc[0][0][1] += __builtin_amdgcn_sqrtf(fmaf(dr_,dr_,di_*di_));
                dr_=COMP(q0A,k)-COMP(t0B,k); di_=COMP(q1A,k)-COMP(t1B,k);
                acc[0][1][0] += __builtin_amdgcn_sqrtf(fmaf(dr_,dr_,di_*di_));
                dr_=COMP(q0B,k)-COMP(t0B,k); di_=COMP(q1B,k)-COMP(t1B,k);
                acc[0][1][1] += __builtin_amdgcn_sqrtf(fmaf(dr_,dr_,di_*di_));
            }
        }
        { // complex: q2·ce_re + q3·ce_im
            float4 q2A=QLOAD(2,bA), q2B=QLOAD(2,bB);
            float4 q3A=QLOAD(3,bA), q3B=QLOAD(3,bB);
            float4 c0A=LD4(ce_re + (size_t)eA*200 + off);
            float4 c0B=LD4(ce_re + (size_t)eB*200 + off);
            float4 c1A=LD4(ce_im + (size_t)eA*200 + off);
            float4 c1B=LD4(ce_im + (size_t)eB*200 + off);
#pragma unroll
            for (int k = 0; k < 4; ++k) {
                acc[1][0][0]=fmaf(COMP(q2A,k),COMP(c0A,k),fmaf(COMP(q3A,k),COMP(c1A,k),acc[1][0][0]));
                acc[1][0][1]=fmaf(COMP(q2B,k),COMP(c0A,k),fmaf(COMP(q3B,k),COMP(c1A,k),acc[1][0][1]));
                acc[1][1][0]=fmaf(COMP(q2A,k),COMP(c0B,k),fmaf(COMP(q3A,k),COMP(c1B,k),acc[1][1][0]));
                acc[1][1][1]=fmaf(COMP(q2B,k),COMP(c0B,k),fmaf(COMP(q3B,k),COMP(c1B,k),acc[1][1][1]));
            }
        }
        { // kdg + distmult
            float4 q4A=QLOAD(4,bA), q4B=QLOAD(4,bB);
            float4 k0A=LD4(ke + (size_t)eA*200 + off);
            float4 k0B=LD4(ke + (size_t)eB*200 + off);
            float4 q5A=QLOAD(5,bA), q5B=QLOAD(5,bB);
            float4 d0A=LD4(de + (size_t)eA*200 + off);
            float4 d0B=LD4(de + (size_t)eB*200 + off);
#pragma unroll
            for (int k = 0; k < 4; ++k) {
                acc[2][0][0]=fmaf(COMP(q4A,k),COMP(k0A,k),acc[2][0][0]);
                acc[2][0][1]=fmaf(COMP(q4B,k),COMP(k0A,k),acc[2][0][1]);
                acc[2][1][0]=fmaf(COMP(q4A,k),COMP(k0B,k),acc[2][1][0]);
                acc[2][1][1]=fmaf(COMP(q4B,k),COMP(k0B,k),acc[2][1][1]);
                acc[3][0][0]=fmaf(COMP(q5A,k),COMP(d0A,k),acc[3][0][0]);
                acc[3][0][1]=fmaf(COMP(q5B,k),COMP(d0A,k),acc[3][0][1]);
                acc[3][1][0]=fmaf(COMP(q5A,k),COMP(d0B,k),acc[3][1][0]);
                acc[3][1][1]=fmaf(COMP(q5B,k),COMP(d0B,k),acc[3][1][1]);
            }
        }
        { // simple: q6·se_t + q7·se_h
            float4 q6A=QLOAD(6,bA), q6B=QLOAD(6,bB);
            float4 s0A=LD4(se_t + (size_t)eA*200 + off);
            float4 s0B=LD4(se_t + (size_t)eB*200 + off);
            float4 q7A=QLOAD(7,bA), q7B=QLOAD(7,bB);
            float4 s1A=LD4(se_h + (size_t)eA*200 + off);
            float4 s1B=LD4(se_h + (size_t)eB*200 + off);
#pragma unroll
            for (int k = 0; k < 4; ++k) {
                acc[4][0][0]=fmaf(COMP(q6A,k),COMP(s0A,k),fmaf(COMP(q7A,k),COMP(s1A,k),acc[4][0][0]));
                acc[4][0][1]=fmaf(COMP(q6B,k),COMP(s0A,k),fmaf(COMP(q7B,k),COMP(s1A,k),acc[4][0][1]));
                acc[4][1][0]=fmaf(COMP(q6A,k),COMP(s0B,k),fmaf(COMP(q7A,k),COMP(s1B,k),acc[4][1][0]));
                acc[4][1][1]=fmaf(COMP(q6B,k),COMP(s0B,k),fmaf(COMP(q7B,k),COMP(s1B,k),acc[4][1][1]));
            }
        }
    };

#pragma unroll 1
    for (int c = 0; c < 6; ++c)      // d = 0..191, always in-bounds
        body(c*32 + ds*4);
    if (ds < 2)                       // tail d = 192..199
        body(192 + ds*4);

    // ---- cross-ds reduction: pure shfl (ds = lane bits 3..5), all lanes end replicated
#pragma unroll
    for (int off2 = 8; off2 <= 32; off2 <<= 1)
#pragma unroll
        for (int m = 0; m < NM; ++m)
#pragma unroll
            for (int je = 0; je < 2; ++je)
#pragma unroll
                for (int jb = 0; jb < 2; ++jb)
                    acc[m][je][jb] += __shfl_xor(acc[m][je][jb], off2, 64);

    float vals[NM][2][2];
#pragma unroll
    for (int m = 0; m < NM; ++m)
#pragma unroll
        for (int je = 0; je < 2; ++je)
#pragma unroll
            for (int jb = 0; jb < 2; ++jb) {
                float v = acc[m][je][jb];
                if (m == 0) v = -v;
                if (m == 4) v = 0.5f * v;
                vals[m][je][jb] = v;
            }

    // ---- S writes: lane with ds==m stores its 4 values (static m, masked) ----
#pragma unroll
    for (int m = 0; m < NM; ++m) {
        if (ds == m) {
            S[(m*8 + bA)*N_ENT + eA] = vals[m][0][0];
            S[(m*8 + bA)*N_ENT + eB] = vals[m][1][0];
            S[(m*8 + bB)*N_ENT + eA] = vals[m][0][1];
            S[(m*8 + bB)*N_ENT + eB] = vals[m][1][1];
        }
    }

    // ---- per-wave stats over 16 e for this wave's 2 b's ----
    float mn2[NM][2], mx2[NM][2], sm2[NM][2], sq2[NM][2];
#pragma unroll
    for (int m = 0; m < NM; ++m)
#pragma unroll
        for (int jb = 0; jb < 2; ++jb) {
            float a = vals[m][0][jb], b = vals[m][1][jb];
            mn2[m][jb] = fminf(a, b);
            mx2[m][jb] = fmaxf(a, b);
            sm2[m][jb] = a + b;
            sq2[m][jb] = fmaf(a, a, b*b);
        }
#pragma unroll
    for (int off2 = 1; off2 <= 4; off2 <<= 1)
#pragma unroll
        for (int m = 0; m < NM; ++m)
#pragma unroll
            for (int jb = 0; jb < 2; ++jb) {
                mn2[m][jb] = fminf(mn2[m][jb], __shfl_xor(mn2[m][jb], off2, 64));
                mx2[m][jb] = fmaxf(mx2[m][jb], __shfl_xor(mx2[m][jb], off2, 64));
                sm2[m][jb] += __shfl_xor(sm2[m][jb], off2, 64);
                sq2[m][jb] += __shfl_xor(sq2[m][jb], off2, 64);
            }
#pragma unroll
    for (int m = 0; m < NM; ++m) {
        if (ds == m && rg == 0) {
#pragma unroll
            for (int jb = 0; jb < 2; ++jb) {
                float4 o = make_float4(mn2[m][jb], mx2[m][jb], sm2[m][jb], sq2[m][jb]);
                *(float4*)(part + (blockIdx.x*40 + m*8 + bA + jb)*4) = o;
            }
        }
    }
}

// ---------------- K_red: parallel reduction of 1250 partials per (m,b) ----------------
__global__ __launch_bounds__(256) void k_red(float* __restrict__ ws)
{
    const float* part = ws + PART_OFF;
    const int p = blockIdx.x;      // 0..39 = m*8+b
    const int t = threadIdx.x;
    __shared__ float  smn[4], smx[4];
    __shared__ double ssm[4], ssq[4];

    float mn = INFINITY, mx = -INFINITY;
    double sm = 0.0, sq = 0.0;
    for (int blk = t; blk < NBLK_MAIN; blk += 256) {
        float4 v = LD4(part + (blk*40 + p)*4);
        mn = fminf(mn, v.x); mx = fmaxf(mx, v.y);
        sm += (double)v.z;   sq += (double)v.w;
    }
#pragma unroll
    for (int off = 1; off < 64; off <<= 1) {
        mn = fminf(mn, __shfl_xor(mn, off, 64));
        mx = fmaxf(mx, __shfl_xor(mx, off, 64));
        sm += __shfl_xor(sm, off, 64);
        sq += __shfl_xor(sq, off, 64);
    }
    if ((t & 63) == 0) {
        smn[t >> 6] = mn; smx[t >> 6] = mx; ssm[t >> 6] = sm; ssq[t >> 6] = sq;
    }
    __syncthreads();
    if (t == 0) {
        mn = fminf(fminf(smn[0], smn[1]), fminf(smn[2], smn[3]));
        mx = fmaxf(fmaxf(smx[0], smx[1]), fmaxf(smx[2], smx[3]));
        sm = ssm[0] + ssm[1] + ssm[2] + ssm[3];
        sq = ssq[0] + ssq[1] + ssq[2] + ssq[3];
        ws[MNMX_OFF + p*2]     = mn;
        ws[MNMX_OFF + p*2 + 1] = mx;
        double* sd = (double*)(ws + STATD_OFF);
        sd[p*2]     = sm;
        sd[p*2 + 1] = sq;
    }
}

// ---------------- K_mlp: features + 5-expert MLP + affine coefficients ----------------
__global__ __launch_bounds__(320) void k_mlp(
    const float* __restrict__ W0, const float* __restrict__ b0,
    const float* __restrict__ W1, const float* __restrict__ b1,
    const float* __restrict__ W2, const float* __restrict__ b2,
    const float* __restrict__ W3, const float* __restrict__ b3,
    float* __restrict__ ws)
{
    __shared__ float feat[NB][10];
    __shared__ float mnS[NM][NB], rngS[NM][NB];
    __shared__ float xA[NM][NB][64], xB[NM][NB][64];
    __shared__ float wS[NM][NB];

    int t = threadIdx.x;
    if (t < 40) {
        int m = t / 8, b = t % 8;
        float  mn = ws[MNMX_OFF + t*2];
        float  mx = ws[MNMX_OFF + t*2 + 1];
        const double* sd = (const double*)(ws + STATD_OFF);
        double sm = sd[t*2], sq = sd[t*2 + 1];
        float  rng  = mx - mn;
        double mean = sm / (double)N_ENT;
        float  md   = 1.0f - (float)((mean - (double)mn) / (double)rng);
        double va   = (sq - sm*sm/(double)N_ENT) / (double)(N_ENT - 1);
        float  vn   = (float)(va / ((double)rng * (double)rng));
        feat[b][2*m]   = md;
        feat[b][2*m+1] = vn;
        mnS[m][b] = mn; rngS[m][b] = rng;
    }
    __syncthreads();

    int ex = t / 64, o = t % 64;
    for (int b = 0; b < NB; ++b) {
        float a = b0[ex*64 + o];
#pragma unroll
        for (int i = 0; i < 10; ++i) a = fmaf(feat[b][i], W0[ex*640 + i*64 + o], a);
        xA[ex][b][o] = a;
    }
    __syncthreads();
    for (int b = 0; b < NB; ++b) {
        float a = b1[ex*64 + o];
        for (int i = 0; i < 64; ++i) a = fmaf(xA[ex][b][i], W1[ex*4096 + i*64 + o], a);
        xB[ex][b][o] = fmaxf(a, 0.f);
    }
    __syncthreads();
    for (int b = 0; b < NB; ++b) {
        float a = b2[ex*64 + o];
        for (int i = 0; i < 64; ++i) a = fmaf(xB[ex][b][i], W2[ex*4096 + i*64 + o], a);
        xA[ex][b][o] = fmaxf(a, 0.f);
    }
    __syncthreads();
    if (o == 0) {
        for (int b = 0; b < NB; ++b) {
            float a = b3[ex];
            for (int i = 0; i < 64; ++i) a = fmaf(xA[ex][b][i], W3[ex*64 + i], a);
            wS[ex][b] = fmaxf(a, 0.f);
        }
    }
    __syncthreads();
    if (t < 8) {
        int b = t;
        float wm = 0.f;
        for (int m = 0; m < NM; ++m) wm = fmaxf(wm, fabsf(wS[m][b]));
        float cst = 0.f;
        for (int m = 0; m < NM; ++m) {
            float w  = wS[m][b] / wm;
            float cc = w / rngS[m][b];
            ws[C_OFF + m*8 + b] = cc;
            cst -= cc * mnS[m][b];
        }
        ws[CONST_OFF + b] = cst;
    }
}

// ---------------- K_combine ----------------
__global__ __launch_bounds__(256) void k_comb(const float* __restrict__ ws,
                                              float* __restrict__ out)
{
    int t = blockIdx.x * 256 + threadIdx.x;
    if (t >= NB * (N_ENT/4)) return;
    int b = t / (N_ENT/4);
    int e = (t % (N_ENT/4)) * 4;
    const float* S = ws + S_OFF;
    float c0 = ws[C_OFF +  0 + b], c1 = ws[C_OFF +  8 + b], c2 = ws[C_OFF + 16 + b];
    float c3 = ws[C_OFF + 24 + b], c4 = ws[C_OFF + 32 + b];
    float cst = ws[CONST_OFF + b];
    float4 s0 = *(const float4*)(S + (0*8 + b)*N_ENT + e);
    float4 s1 = *(const float4*)(S + (1*8 + b)*N_ENT + e);
    float4 s2 = *(const float4*)(S + (2*8 + b)*N_ENT + e);
    float4 s3 = *(const float4*)(S + (3*8 + b)*N_ENT + e);
    float4 s4 = *(const float4*)(S + (4*8 + b)*N_ENT + e);
    float4 o4;
    o4.x = fmaf(c0,s0.x, fmaf(c1,s1.x, fmaf(c2,s2.x, fmaf(c3,s3.x, fmaf(c4,s4.x, cst)))));
    o4.y = fmaf(c0,s0.y, fmaf(c1,s1.y, fmaf(c2,s2.y, fmaf(c3,s3.y, fmaf(c4,s4.y, cst)))));
    o4.z = fmaf(c0,s0.z, fmaf(c1,s1.z, fmaf(c2,s2.z, fmaf(c3,s3.z, fmaf(c4,s4.z, cst)))));
    o4.w = fmaf(c0,s0.w, fmaf(c1,s1.w, fmaf(c2,s2.w, fmaf(c3,s3.w, fmaf(c4,s4.w, cst)))));
    *(float4*)(out + b*N_ENT + e) = o4;
}

extern "C" void kernel_launch(void* const* d_in, const int* in_sizes, int n_in,
                              void* d_out, int out_size, void* d_ws, size_t ws_size,
                              hipStream_t stream)
{
    const int*   batch  = (const int*)  d_in[0];
    const float* eemb   = (const float*)d_in[1];
    const float* remb   = (const float*)d_in[2];
    const float* ce_re  = (const float*)d_in[3];
    const float* ce_im  = (const float*)d_in[4];
    const float* cr_re  = (const float*)d_in[5];
    const float* cr_im  = (const float*)d_in[6];
    const float* de     = (const float*)d_in[7];
    const float* dr     = (const float*)d_in[8];
    const float* ke     = (const float*)d_in[9];
    const float* kr     = (const float*)d_in[10];
    const float* se_h   = (const float*)d_in[11];
    const float* se_t   = (const float*)d_in[12];
    const float* sr     = (const float*)d_in[13];
    const float* sr_inv = (const float*)d_in[14];
    const float* W0 = (const float*)d_in[15];
    const float* b0 = (const float*)d_in[16];
    const float* W1 = (const float*)d_in[17];
    const float* b1 = (const float*)d_in[18];
    const float* W2 = (const float*)d_in[19];
    const float* b2 = (const float*)d_in[20];
    const float* W3 = (const float*)d_in[21];
    const float* b3 = (const float*)d_in[22];
    float* ws  = (float*)d_ws;
    float* out = (float*)d_out;

    k_q    <<<8, 256, 0, stream>>>(batch, eemb, remb, ce_re, ce_im, cr_re, cr_im,
                                   de, dr, ke, kr, se_h, se_t, sr, sr_inv, ws);
    k_main <<<NBLK_MAIN, 256, 0, stream>>>(eemb, ce_re, ce_im, ke, de, se_h, se_t, ws);
    k_red  <<<40, 256, 0, stream>>>(ws);
    k_mlp  <<<1, 320, 0, stream>>>(W0, b0, W1, b1, W2, b2, W3, b3, ws);
    k_comb <<<(NB*(N_ENT/4) + 255)/256, 256, 0, stream>>>(ws, out);
}

// Round 11
// 79.679 us; speedup vs baseline: 1.4009x; 1.4009x over previous
//
#include <hip/hip_runtime.h>
#include <math.h>

#define N_ENT 20000
#define D 200
#define NB 8
#define NM 5
#define NBLK_MAIN 1250   // 16 entities per block

// ws layout (in floats)
#define Q_OFF     0        // 8 vec * 8 b * 200 = 12800
#define PART_OFF  12800    // 1250 blocks * 40 pairs * 4 = 200000
#define MNMX_OFF  212800   // 40 * 2 floats
#define STATD_OFF 212880   // 40 * 2 doubles = 160 floats
#define C_OFF     213040   // 40
#define CONST_OFF 213080   // 8
#define S_OFF     213088   // 5*8*20000 = 800000

#define COMP(v,j) ((j)==0 ? (v).x : (j)==1 ? (v).y : (j)==2 ? (v).z : (v).w)
#define LD4(p) (*(const float4*)(p))

// ---------------- K_q: build 8 per-b query vectors into ws ----------------
__global__ __launch_bounds__(256) void k_q(
    const int* __restrict__ batch, const float* __restrict__ eemb,
    const float* __restrict__ remb,
    const float* __restrict__ ce_re, const float* __restrict__ ce_im,
    const float* __restrict__ cr_re, const float* __restrict__ cr_im,
    const float* __restrict__ de, const float* __restrict__ dr,
    const float* __restrict__ ke, const float* __restrict__ kr,
    const float* __restrict__ se_h, const float* __restrict__ se_t,
    const float* __restrict__ sr, const float* __restrict__ sr_inv,
    float* __restrict__ ws)
{
    int b = blockIdx.x;
    int d = threadIdx.x;
    if (d >= D) return;
    int h = batch[b*48 + 0];
    int r = batch[b*48 + 2];
    float* q = ws + Q_OFF;

    float her = eemb[h*400 + d];
    float hei = eemb[h*400 + 200 + d];
    float ph  = remb[r*200 + d];
    float cph = cosf(ph), sph = sinf(ph);
    q[(0*8 + b)*200 + d] = her*cph - hei*sph;          // p_re
    q[(1*8 + b)*200 + d] = her*sph + hei*cph;          // p_im

    float cer = ce_re[h*200+d], cei = ce_im[h*200+d];
    float crr = cr_re[r*200+d], cri = cr_im[r*200+d];
    q[(2*8 + b)*200 + d] = cer*crr - cei*cri;          // s_re
    q[(3*8 + b)*200 + d] = cer*cri + cei*crr;          // s_im

    q[(4*8 + b)*200 + d] = ke[h*200+d] * kr[r*200+d];
    q[(5*8 + b)*200 + d] = de[h*200+d] * dr[r*200+d];
    q[(6*8 + b)*200 + d] = se_h[h*200+d] * sr[r*200+d];     // pairs with se_t[e]
    q[(7*8 + b)*200 + d] = se_t[h*200+d] * sr_inv[r*200+d]; // pairs with se_h[e]
}

// ---------------- K_main v11 = v5 minus qbuf ----------------
// 256 threads = 4 waves. thread = (ds = tid>>5 : d-quad, rg = (tid>>2)&7 : e-pair,
// bg = tid&3 : b-pair). Register tile 2e x 2b, acc[5][2][2].
// LDS: ebuf [2][8 arr][16 e][32 d] (32 KB) only — qbuf removed (v5's 48.6 KB capped
// the CU at 2 blocks; 33.4 KB fits 4 blocks/CU = 16 waves). q read direct from
// ws (L1/L2-resident 51 KB; 4 small segments per wave-instr, rg broadcasts).
// E staging: swizzled global_load_lds, double-buffered, 1-deep prefetch (as v5).
__global__ __launch_bounds__(256, 4) void k_main(
    const float* __restrict__ eemb, const float* __restrict__ ce_re,
    const float* __restrict__ ce_im, const float* __restrict__ ke,
    const float* __restrict__ de, const float* __restrict__ se_h,
    const float* __restrict__ se_t, float* __restrict__ ws)
{
    __shared__ __align__(16) float ebuf[2][8][16][32];   // 32 KB
    __shared__ float4 red2[2][40];

    const float* qg = ws + Q_OFF;
    float* S    = ws + S_OFF;
    float* part = ws + PART_OFF;

    const int tid = threadIdx.x;
    const int wv  = tid >> 6;        // wave 0..3
    const int l   = tid & 63;
    const int bg  = tid & 3;         // b-pair: b = 2bg+jb
    const int rg  = (tid >> 2) & 7;  // e-pair: e = 2rg+je
    const int ds  = tid >> 5;        // d-quad 0..7 within chunk
    const int e0  = blockIdx.x * 16;

    // this wave's two staged arrays
    const float *gb0, *gb1; int gs0, go0, gs1, go1;
    switch (wv) {
        case 0: gb0 = eemb;  gs0 = 400; go0 = 0; gb1 = eemb;  gs1 = 400; go1 = 200; break;
        case 1: gb0 = ce_re; gs0 = 200; go0 = 0; gb1 = ce_im; gs1 = 200; go1 = 0;   break;
        case 2: gb0 = ke;    gs0 = 200; go0 = 0; gb1 = de;    gs1 = 200; go1 = 0;   break;
        default:gb0 = se_t;  gs0 = 200; go0 = 0; gb1 = se_h;  gs1 = 200; go1 = 0;   break;
    }
    const int sl = l & 7;     // 16B slot within 128B row-chunk
    const int rl = l >> 3;    // row within 8-row group

    auto stage = [&](int buf, int c) {
#pragma unroll
        for (int a = 0; a < 2; ++a) {
            const float* gbase = a ? gb1 : gb0;
            const int gs_ = a ? gs1 : gs0, go_ = a ? go1 : go0;
#pragma unroll
            for (int i = 0; i < 2; ++i) {
                int rr  = i*8 + rl;
                int col = c*32 + ((sl ^ (rr & 7)) << 2);
                if (col + 4 > 200) col = 0;                // tail clamp (unused content)
                const float* gp = gbase + (size_t)(e0 + rr) * gs_ + go_ + col;
                float* lp = &ebuf[buf][2*wv + a][i*8][0];
                __builtin_amdgcn_global_load_lds(
                    (const __attribute__((address_space(1))) void*)gp,
                    (__attribute__((address_space(3))) void*)lp, 16, 0, 0);
            }
        }
    };

    float acc[NM][2][2];
#pragma unroll
    for (int m = 0; m < NM; ++m)
#pragma unroll
        for (int je = 0; je < 2; ++je)
#pragma unroll
            for (int jb = 0; jb < 2; ++jb) acc[m][je][jb] = 0.f;

    const int eA = 2*rg, eB = 2*rg + 1;
    const int bA = 2*bg, bB = 2*bg + 1;
    const int peA = ((ds ^ (eA & 7)) << 2), peB = ((ds ^ (eB & 7)) << 2);

    stage(0, 0);
    for (int c = 0; c < 7; ++c) {
        __syncthreads();                       // stage(c) complete
        if (c < 6) stage((c+1)&1, c+1);        // 1-deep prefetch into other buffer
        const int off = c*32 + ds*4;
        if (off < 200) {
            const float* eb = &ebuf[c&1][0][0][0];
#define ELOAD(arr, pe, e) LD4(eb + (((arr)*16 + (e))*32) + (pe))
#define QLOAD(v, b)       LD4(qg + ((v)*8 + (b))*200 + off)
            { // rotate: q0 (p_re), q1 (p_im) vs t_re, t_im
                float4 q0A=QLOAD(0,bA), q0B=QLOAD(0,bB);
                float4 q1A=QLOAD(1,bA), q1B=QLOAD(1,bB);
                float4 t0A=ELOAD(0,peA,eA), t0B=ELOAD(0,peB,eB);
                float4 t1A=ELOAD(1,peA,eA), t1B=ELOAD(1,peB,eB);
#pragma unroll
                for (int k = 0; k < 4; ++k) {
                    float dr_, di_;
                    dr_=COMP(q0A,k)-COMP(t0A,k); di_=COMP(q1A,k)-COMP(t1A,k);
                    acc[0][0][0] += __builtin_amdgcn_sqrtf(fmaf(dr_,dr_,di_*di_));
                    dr_=COMP(q0B,k)-COMP(t0A,k); di_=COMP(q1B,k)-COMP(t1A,k);
                    acc[0][0][1] += __builtin_amdgcn_sqrtf(fmaf(dr_,dr_,di_*di_));
                    dr_=COMP(q0A,k)-COMP(t0B,k); di_=COMP(q1A,k)-COMP(t1B,k);
                    acc[0][1][0] += __builtin_amdgcn_sqrtf(fmaf(dr_,dr_,di_*di_));
                    dr_=COMP(q0B,k)-COMP(t0B,k); di_=COMP(q1B,k)-COMP(t1B,k);
                    acc[0][1][1] += __builtin_amdgcn_sqrtf(fmaf(dr_,dr_,di_*di_));
                }
            }
            { // complex: q2·ce_re + q3·ce_im
                float4 q2A=QLOAD(2,bA), q2B=QLOAD(2,bB);
                float4 q3A=QLOAD(3,bA), q3B=QLOAD(3,bB);
                float4 c0A=ELOAD(2,peA,eA), c0B=ELOAD(2,peB,eB);
                float4 c1A=ELOAD(3,peA,eA), c1B=ELOAD(3,peB,eB);
#pragma unroll
                for (int k = 0; k < 4; ++k) {
                    acc[1][0][0]=fmaf(COMP(q2A,k),COMP(c0A,k),fmaf(COMP(q3A,k),COMP(c1A,k),acc[1][0][0]));
                    acc[1][0][1]=fmaf(COMP(q2B,k),COMP(c0A,k),fmaf(COMP(q3B,k),COMP(c1A,k),acc[1][0][1]));
                    acc[1][1][0]=fmaf(COMP(q2A,k),COMP(c0B,k),fmaf(COMP(q3A,k),COMP(c1B,k),acc[1][1][0]));
                    acc[1][1][1]=fmaf(COMP(q2B,k),COMP(c0B,k),fmaf(COMP(q3B,k),COMP(c1B,k),acc[1][1][1]));
                }
            }
            { // kdg + distmult
                float4 q4A=QLOAD(4,bA), q4B=QLOAD(4,bB);
                float4 k0A=ELOAD(4,peA,eA), k0B=ELOAD(4,peB,eB);
                float4 q5A=QLOAD(5,bA), q5B=QLOAD(5,bB);
                float4 d0A=ELOAD(5,peA,eA), d0B=ELOAD(5,peB,eB);
#pragma unroll
                for (int k = 0; k < 4; ++k) {
                    acc[2][0][0]=fmaf(COMP(q4A,k),COMP(k0A,k),acc[2][0][0]);
                    acc[2][0][1]=fmaf(COMP(q4B,k),COMP(k0A,k),acc[2][0][1]);
                    acc[2][1][0]=fmaf(COMP(q4A,k),COMP(k0B,k),acc[2][1][0]);
                    acc[2][1][1]=fmaf(COMP(q4B,k),COMP(k0B,k),acc[2][1][1]);
                    acc[3][0][0]=fmaf(COMP(q5A,k),COMP(d0A,k),acc[3][0][0]);
                    acc[3][0][1]=fmaf(COMP(q5B,k),COMP(d0A,k),acc[3][0][1]);
                    acc[3][1][0]=fmaf(COMP(q5A,k),COMP(d0B,k),acc[3][1][0]);
                    acc[3][1][1]=fmaf(COMP(q5B,k),COMP(d0B,k),acc[3][1][1]);
                }
            }
            { // simple: q6·se_t + q7·se_h
                float4 q6A=QLOAD(6,bA), q6B=QLOAD(6,bB);
                float4 q7A=QLOAD(7,bA), q7B=QLOAD(7,bB);
                float4 s0A=ELOAD(6,peA,eA), s0B=ELOAD(6,peB,eB);
                float4 s1A=ELOAD(7,peA,eA), s1B=ELOAD(7,peB,eB);
#pragma unroll
                for (int k = 0; k < 4; ++k) {
                    acc[4][0][0]=fmaf(COMP(q6A,k),COMP(s0A,k),fmaf(COMP(q7A,k),COMP(s1A,k),acc[4][0][0]));
                    acc[4][0][1]=fmaf(COMP(q6B,k),COMP(s0A,k),fmaf(COMP(q7B,k),COMP(s1A,k),acc[4][0][1]));
                    acc[4][1][0]=fmaf(COMP(q6A,k),COMP(s0B,k),fmaf(COMP(q7A,k),COMP(s1B,k),acc[4][1][0]));
                    acc[4][1][1]=fmaf(COMP(q6B,k),COMP(s0B,k),fmaf(COMP(q7B,k),COMP(s1B,k),acc[4][1][1]));
                }
            }
        }
    }

    // ---- cross-ds reduction via LDS overlay on ebuf ----
    __syncthreads();
    float* ov = &ebuf[0][0][0][0];   // 256 threads * 20 floats = 5120 < 8192
    {
        int base = tid * 20;
#pragma unroll
        for (int m = 0; m < NM; ++m)
#pragma unroll
            for (int je = 0; je < 2; ++je)
#pragma unroll
                for (int jb = 0; jb < 2; ++jb)
                    ov[base + m*4 + je*2 + jb] = acc[m][je][jb];
    }
    __syncthreads();
    if (tid < 128) {
        int e_l = tid >> 3, b = tid & 7;
        int rg2 = e_l >> 1, je = e_l & 1, bg2 = b >> 1, jb = b & 1;
        float vals[NM];
#pragma unroll
        for (int m = 0; m < NM; ++m) {
            float s = 0.f;
#pragma unroll
            for (int d2 = 0; d2 < 8; ++d2)
                s += ov[((d2 << 5) | (rg2 << 2) | bg2) * 20 + m*4 + je*2 + jb];
            vals[m] = s;
        }
        vals[0] = -vals[0];
        vals[4] = 0.5f * vals[4];
        int e = e0 + e_l;
#pragma unroll
        for (int m = 0; m < NM; ++m) S[(m*8 + b)*N_ENT + e] = vals[m];

        float mn[NM], mx[NM], sm[NM], sq[NM];
#pragma unroll
        for (int m = 0; m < NM; ++m) {
            mn[m] = vals[m]; mx[m] = vals[m]; sm[m] = vals[m]; sq[m] = vals[m]*vals[m];
        }
#pragma unroll
        for (int off = 8; off <= 32; off <<= 1) {
#pragma unroll
            for (int m = 0; m < NM; ++m) {
                mn[m] = fminf(mn[m], __shfl_xor(mn[m], off, 64));
                mx[m] = fmaxf(mx[m], __shfl_xor(mx[m], off, 64));
                sm[m] += __shfl_xor(sm[m], off, 64);
                sq[m] += __shfl_xor(sq[m], off, 64);
            }
        }
        if ((tid & 63) < 8) {   // lane b = tid&7, e-half = tid>>6
#pragma unroll
            for (int m = 0; m < NM; ++m)
                red2[tid >> 6][m*8 + b] = make_float4(mn[m], mx[m], sm[m], sq[m]);
        }
    }
    __syncthreads();
    if (tid < 40) {
        float4 u = red2[0][tid], v = red2[1][tid];
        float4 o;
        o.x = fminf(u.x, v.x);
        o.y = fmaxf(u.y, v.y);
        o.z = u.z + v.z;
        o.w = u.w + v.w;
        *(float4*)(part + (blockIdx.x*40 + tid)*4) = o;
    }
}

// ---------------- K_red: parallel reduction of 1250 partials per (m,b) ----------------
__global__ __launch_bounds__(256) void k_red(float* __restrict__ ws)
{
    const float* part = ws + PART_OFF;
    const int p = blockIdx.x;      // 0..39 = m*8+b
    const int t = threadIdx.x;
    __shared__ float  smn[4], smx[4];
    __shared__ double ssm[4], ssq[4];

    float mn = INFINITY, mx = -INFINITY;
    double sm = 0.0, sq = 0.0;
    for (int blk = t; blk < NBLK_MAIN; blk += 256) {
        float4 v = LD4(part + (blk*40 + p)*4);
        mn = fminf(mn, v.x); mx = fmaxf(mx, v.y);
        sm += (double)v.z;   sq += (double)v.w;
    }
#pragma unroll
    for (int off = 1; off < 64; off <<= 1) {
        mn = fminf(mn, __shfl_xor(mn, off, 64));
        mx = fmaxf(mx, __shfl_xor(mx, off, 64));
        sm += __shfl_xor(sm, off, 64);
        sq += __shfl_xor(sq, off, 64);
    }
    if ((t & 63) == 0) {
        smn[t >> 6] = mn; smx[t >> 6] = mx; ssm[t >> 6] = sm; ssq[t >> 6] = sq;
    }
    __syncthreads();
    if (t == 0) {
        mn = fminf(fminf(smn[0], smn[1]), fminf(smn[2], smn[3]));
        mx = fmaxf(fmaxf(smx[0], smx[1]), fmaxf(smx[2], smx[3]));
        sm = ssm[0] + ssm[1] + ssm[2] + ssm[3];
        sq = ssq[0] + ssq[1] + ssq[2] + ssq[3];
        ws[MNMX_OFF + p*2]     = mn;
        ws[MNMX_OFF + p*2 + 1] = mx;
        double* sd = (double*)(ws + STATD_OFF);
        sd[p*2]     = sm;
        sd[p*2 + 1] = sq;
    }
}

// ---------------- K_mlp: features + 5-expert MLP + affine coefficients ----------------
__global__ __launch_bounds__(320) void k_mlp(
    const float* __restrict__ W0, const float* __restrict__ b0,
    const float* __restrict__ W1, const float* __restrict__ b1,
    const float* __restrict__ W2, const float* __restrict__ b2,
    const float* __restrict__ W3, const float* __restrict__ b3,
    float* __restrict__ ws)
{
    __shared__ float feat[NB][10];
    __shared__ float mnS[NM][NB], rngS[NM][NB];
    __shared__ float xA[NM][NB][64], xB[NM][NB][64];
    __shared__ float wS[NM][NB];

    int t = threadIdx.x;
    if (t < 40) {
        int m = t / 8, b = t % 8;
        float  mn = ws[MNMX_OFF + t*2];
        float  mx = ws[MNMX_OFF + t*2 + 1];
        const double* sd = (const double*)(ws + STATD_OFF);
        double sm = sd[t*2], sq = sd[t*2 + 1];
        float  rng  = mx - mn;
        double mean = sm / (double)N_ENT;
        float  md   = 1.0f - (float)((mean - (double)mn) / (double)rng);
        double va   = (sq - sm*sm/(double)N_ENT) / (double)(N_ENT - 1);
        float  vn   = (float)(va / ((double)rng * (double)rng));
        feat[b][2*m]   = md;
        feat[b][2*m+1] = vn;
        mnS[m][b] = mn; rngS[m][b] = rng;
    }
    __syncthreads();

    int ex = t / 64, o = t % 64;
    for (int b = 0; b < NB; ++b) {
        float a = b0[ex*64 + o];
#pragma unroll
        for (int i = 0; i < 10; ++i) a = fmaf(feat[b][i], W0[ex*640 + i*64 + o], a);
        xA[ex][b][o] = a;
    }
    __syncthreads();
    for (int b = 0; b < NB; ++b) {
        float a = b1[ex*64 + o];
        for (int i = 0; i < 64; ++i) a = fmaf(xA[ex][b][i], W1[ex*4096 + i*64 + o], a);
        xB[ex][b][o] = fmaxf(a, 0.f);
    }
    __syncthreads();
    for (int b = 0; b < NB; ++b) {
        float a = b2[ex*64 + o];
        for (int i = 0; i < 64; ++i) a = fmaf(xB[ex][b][i], W2[ex*4096 + i*64 + o], a);
        xA[ex][b][o] = fmaxf(a, 0.f);
    }
    __syncthreads();
    if (o == 0) {
        for (int b = 0; b < NB; ++b) {
            float a = b3[ex];
            for (int i = 0; i < 64; ++i) a = fmaf(xA[ex][b][i], W3[ex*64 + i], a);
            wS[ex][b] = fmaxf(a, 0.f);
        }
    }
    __syncthreads();
    if (t < 8) {
        int b = t;
        float wm = 0.f;
        for (int m = 0; m < NM; ++m) wm = fmaxf(wm, fabsf(wS[m][b]));
        float cst = 0.f;
        for (int m = 0; m < NM; ++m) {
            float w  = wS[m][b] / wm;
            float cc = w / rngS[m][b];
            ws[C_OFF + m*8 + b] = cc;
            cst -= cc * mnS[m][b];
        }
        ws[CONST_OFF + b] = cst;
    }
}

// ---------------- K_combine ----------------
__global__ __launch_bounds__(256) void k_comb(const float* __restrict__ ws,
                                              float* __restrict__ out)
{
    int t = blockIdx.x * 256 + threadIdx.x;
    if (t >= NB * (N_ENT/4)) return;
    int b = t / (N_ENT/4);
    int e = (t % (N_ENT/4)) * 4;
    const float* S = ws + S_OFF;
    float c0 = ws[C_OFF +  0 + b], c1 = ws[C_OFF +  8 + b], c2 = ws[C_OFF + 16 + b];
    float c3 = ws[C_OFF + 24 + b], c4 = ws[C_OFF + 32 + b];
    float cst = ws[CONST_OFF + b];
    float4 s0 = *(const float4*)(S + (0*8 + b)*N_ENT + e);
    float4 s1 = *(const float4*)(S + (1*8 + b)*N_ENT + e);
    float4 s2 = *(const float4*)(S + (2*8 + b)*N_ENT + e);
    float4 s3 = *(const float4*)(S + (3*8 + b)*N_ENT + e);
    float4 s4 = *(const float4*)(S + (4*8 + b)*N_ENT + e);
    float4 o4;
    o4.x = fmaf(c0,s0.x, fmaf(c1,s1.x, fmaf(c2,s2.x, fmaf(c3,s3.x, fmaf(c4,s4.x, cst)))));
    o4.y = fmaf(c0,s0.y, fmaf(c1,s1.y, fmaf(c2,s2.y, fmaf(c3,s3.y, fmaf(c4,s4.y, cst)))));
    o4.z = fmaf(c0,s0.z, fmaf(c1,s1.z, fmaf(c2,s2.z, fmaf(c3,s3.z, fmaf(c4,s4.z, cst)))));
    o4.w = fmaf(c0,s0.w, fmaf(c1,s1.w, fmaf(c2,s2.w, fmaf(c3,s3.w, fmaf(c4,s4.w, cst)))));
    *(float4*)(out + b*N_ENT + e) = o4;
}

extern "C" void kernel_launch(void* const* d_in, const int* in_sizes, int n_in,
                              void* d_out, int out_size, void* d_ws, size_t ws_size,
                              hipStream_t stream)
{
    const int*   batch  = (const int*)  d_in[0];
    const float* eemb   = (const float*)d_in[1];
    const float* remb   = (const float*)d_in[2];
    const float* ce_re  = (const float*)d_in[3];
    const float* ce_im  = (const float*)d_in[4];
    const float* cr_re  = (const float*)d_in[5];
    const float* cr_im  = (const float*)d_in[6];
    const float* de     = (const float*)d_in[7];
    const float* dr     = (const float*)d_in[8];
    const float* ke     = (const float*)d_in[9];
    const float* kr     = (const float*)d_in[10];
    const float* se_h   = (const float*)d_in[11];
    const float* se_t   = (const float*)d_in[12];
    const float* sr     = (const float*)d_in[13];
    const float* sr_inv = (const float*)d_in[14];
    const float* W0 = (const float*)d_in[15];
    const float* b0 = (const float*)d_in[16];
    const float* W1 = (const float*)d_in[17];
    const float* b1 = (const float*)d_in[18];
    const float* W2 = (const float*)d_in[19];
    const float* b2 = (const float*)d_in[20];
    const float* W3 = (const float*)d_in[21];
    const float* b3 = (const float*)d_in[22];
    float* ws  = (float*)d_ws;
    float* out = (float*)d_out;

    k_q    <<<8, 256, 0, stream>>>(batch, eemb, remb, ce_re, ce_im, cr_re, cr_im,
                                   de, dr, ke, kr, se_h, se_t, sr, sr_inv, ws);
    k_main <<<NBLK_MAIN, 256, 0, stream>>>(eemb, ce_re, ce_im, ke, de, se_h, se_t, ws);
    k_red  <<<40, 256, 0, stream>>>(ws);
    k_mlp  <<<1, 320, 0, stream>>>(W0, b0, W1, b1, W2, b2, W3, b3, ws);
    k_comb <<<(NB*(N_ENT/4) + 255)/256, 256, 0, stream>>>(ws, out);
}

// Round 12
// 68.024 us; speedup vs baseline: 1.6409x; 1.1713x over previous
//
#include <hip/hip_runtime.h>
#include <math.h>

#define N_ENT 20000
#define D 200
#define NB 8
#define NM 5
#define NBLK_MAIN 625    // 32 entities per block

// ws layout (in floats)
#define Q_OFF     0        // 8 vec * 8 b * 200 = 12800
#define PART_OFF  12800    // 625 blocks * 40 pairs * 4 = 100000
#define MNMX_OFF  212800   // 40 * 2 floats
#define STATD_OFF 212880   // 40 * 2 doubles = 160 floats
#define C_OFF     213040   // 40
#define CONST_OFF 213080   // 8
#define S_OFF     213088   // 5*8*20000 = 800000

#define COMP(v,j) ((j)==0 ? (v).x : (j)==1 ? (v).y : (j)==2 ? (v).z : (v).w)
#define LD4(p) (*(const float4*)(p))

// ---------------- K_q: build 8 per-b query vectors into ws ----------------
__global__ __launch_bounds__(256) void k_q(
    const int* __restrict__ batch, const float* __restrict__ eemb,
    const float* __restrict__ remb,
    const float* __restrict__ ce_re, const float* __restrict__ ce_im,
    const float* __restrict__ cr_re, const float* __restrict__ cr_im,
    const float* __restrict__ de, const float* __restrict__ dr,
    const float* __restrict__ ke, const float* __restrict__ kr,
    const float* __restrict__ se_h, const float* __restrict__ se_t,
    const float* __restrict__ sr, const float* __restrict__ sr_inv,
    float* __restrict__ ws)
{
    int b = blockIdx.x;
    int d = threadIdx.x;
    if (d >= D) return;
    int h = batch[b*48 + 0];
    int r = batch[b*48 + 2];
    float* q = ws + Q_OFF;

    float her = eemb[h*400 + d];
    float hei = eemb[h*400 + 200 + d];
    float ph  = remb[r*200 + d];
    float cph = cosf(ph), sph = sinf(ph);
    q[(0*8 + b)*200 + d] = her*cph - hei*sph;          // p_re
    q[(1*8 + b)*200 + d] = her*sph + hei*cph;          // p_im

    float cer = ce_re[h*200+d], cei = ce_im[h*200+d];
    float crr = cr_re[r*200+d], cri = cr_im[r*200+d];
    q[(2*8 + b)*200 + d] = cer*crr - cei*cri;          // s_re
    q[(3*8 + b)*200 + d] = cer*cri + cei*crr;          // s_im

    q[(4*8 + b)*200 + d] = ke[h*200+d] * kr[r*200+d];
    q[(5*8 + b)*200 + d] = de[h*200+d] * dr[r*200+d];
    q[(6*8 + b)*200 + d] = se_h[h*200+d] * sr[r*200+d];     // pairs with se_t[e]
    q[(7*8 + b)*200 + d] = se_t[h*200+d] * sr_inv[r*200+d]; // pairs with se_h[e]
}

// ---------------- K_main v12 = v5 engine, 2x tile ----------------
// 512 threads = 8 waves, 32 entities/block. thread: ds = tid>>6 (wave, d-quad,
// WAVE-UNIFORM), rg = (tid>>2)&15 (e-pair), bg = tid&3 (b-pair). acc[5][2][2].
// LDS 80 KB: ebuf [2][8 arr][32 e][32 d] (64K) + qbuf [2][8 vec][8 b][32 d] (16K)
// -> 2 blocks/CU = 16 waves/CU (2x v5) and half the barriers/entity.
// Staging: wave w stages e-array w (4 instr) + q-vec w (1 instr), XOR-swizzled
// via pre-swizzled GLOBAL source cols (LDS dest linear). Verified mapping:
// read slot ds^(row&7) o write slot sl^(row&7) = column ds.
__global__ __launch_bounds__(512, 4) void k_main(
    const float* __restrict__ eemb, const float* __restrict__ ce_re,
    const float* __restrict__ ce_im, const float* __restrict__ ke,
    const float* __restrict__ de, const float* __restrict__ se_h,
    const float* __restrict__ se_t, float* __restrict__ ws)
{
    __shared__ __align__(16) float ebuf[2][8][32][32];   // 64 KB
    __shared__ __align__(16) float qbuf[2][8][8][32];    // 16 KB

    const float* qg = ws + Q_OFF;
    float* S    = ws + S_OFF;
    float* part = ws + PART_OFF;

    const int tid = threadIdx.x;
    const int wv  = tid >> 6;        // wave 0..7 = staged array = ds
    const int l   = tid & 63;
    const int bg  = tid & 3;         // b-pair: b = 2bg+jb
    const int rg  = (tid >> 2) & 15; // e-pair: e = 2rg+je
    const int ds  = wv;              // d-quad 0..7 within chunk (wave-uniform)
    const int e0  = blockIdx.x * 32;

    // this wave's staged e-array
    const float* gb; int gs, go;
    switch (wv) {
        case 0: gb = eemb;  gs = 400; go = 0;   break;  // t_re
        case 1: gb = eemb;  gs = 400; go = 200; break;  // t_im
        case 2: gb = ce_re; gs = 200; go = 0;   break;
        case 3: gb = ce_im; gs = 200; go = 0;   break;
        case 4: gb = ke;    gs = 200; go = 0;   break;
        case 5: gb = de;    gs = 200; go = 0;   break;
        case 6: gb = se_t;  gs = 200; go = 0;   break;
        default:gb = se_h;  gs = 200; go = 0;   break;
    }
    const int sl = l & 7;     // 16B slot within 128B row-chunk
    const int rl = l >> 3;    // row within 8-row group

    auto stage = [&](int buf, int c) {
#pragma unroll
        for (int i = 0; i < 4; ++i) {             // 32 entity rows
            int rr  = i*8 + rl;
            int col = c*32 + ((sl ^ (rr & 7)) << 2);
            if (col + 4 > 200) col = 0;           // tail clamp (unused content)
            const float* gp = gb + (size_t)(e0 + rr) * gs + go + col;
            float* lp = &ebuf[buf][wv][i*8][0];
            __builtin_amdgcn_global_load_lds(
                (const __attribute__((address_space(1))) void*)gp,
                (__attribute__((address_space(3))) void*)lp, 16, 0, 0);
        }
        {                                          // q vector wv (8 b rows)
            int col = c*32 + ((sl ^ rl) << 2);
            if (col + 4 > 200) col = 0;
            const float* gp = qg + (size_t)(wv*8 + rl) * 200 + col;
            float* lp = &qbuf[buf][wv][0][0];
            __builtin_amdgcn_global_load_lds(
                (const __attribute__((address_space(1))) void*)gp,
                (__attribute__((address_space(3))) void*)lp, 16, 0, 0);
        }
    };

    float acc[NM][2][2];
#pragma unroll
    for (int m = 0; m < NM; ++m)
#pragma unroll
        for (int je = 0; je < 2; ++je)
#pragma unroll
            for (int jb = 0; jb < 2; ++jb) acc[m][je][jb] = 0.f;

    const int eA = 2*rg, eB = 2*rg + 1;
    const int bA = 2*bg, bB = 2*bg + 1;
    const int peA = ((ds ^ (eA & 7)) << 2), peB = ((ds ^ (eB & 7)) << 2);
    const int pqA = ((ds ^ bA) << 2),       pqB = ((ds ^ bB) << 2);

    stage(0, 0);
    for (int c = 0; c < 7; ++c) {
        __syncthreads();                       // stage(c) complete
        if (c < 6) stage((c+1)&1, c+1);        // 1-deep prefetch into other buffer
        const int off = c*32 + ds*4;
        if (off < 200) {                       // wave-uniform (ds = wave id)
            const float* eb = &ebuf[c&1][0][0][0];
            const float* qb = &qbuf[c&1][0][0][0];
#define ELOAD(arr, pe, e) LD4(eb + (((arr)*32 + (e))*32) + (pe))
#define QLOAD(v, pq, b)   LD4(qb + (((v)*8 + (b)) << 5) + (pq))
            { // rotate: q0 (p_re), q1 (p_im) vs t_re, t_im
                float4 q0A=QLOAD(0,pqA,bA), q0B=QLOAD(0,pqB,bB);
                float4 q1A=QLOAD(1,pqA,bA), q1B=QLOAD(1,pqB,bB);
                float4 t0A=ELOAD(0,peA,eA), t0B=ELOAD(0,peB,eB);
                float4 t1A=ELOAD(1,peA,eA), t1B=ELOAD(1,peB,eB);
#pragma unroll
                for (int k = 0; k < 4; ++k) {
                    float dr_, di_;
                    dr_=COMP(q0A,k)-COMP(t0A,k); di_=COMP(q1A,k)-COMP(t1A,k);
                    acc[0][0][0] += __builtin_amdgcn_sqrtf(fmaf(dr_,dr_,di_*di_));
                    dr_=COMP(q0B,k)-COMP(t0A,k); di_=COMP(q1B,k)-COMP(t1A,k);
                    acc[0][0][1] += __builtin_amdgcn_sqrtf(fmaf(dr_,dr_,di_*di_));
                    dr_=COMP(q0A,k)-COMP(t0B,k); di_=COMP(q1A,k)-COMP(t1B,k);
                    acc[0][1][0] += __builtin_amdgcn_sqrtf(fmaf(dr_,dr_,di_*di_));
                    dr_=COMP(q0B,k)-COMP(t0B,k); di_=COMP(q1B,k)-COMP(t1B,k);
                    acc[0][1][1] += __builtin_amdgcn_sqrtf(fmaf(dr_,dr_,di_*di_));
                }
            }
            { // complex: q2·ce_re + q3·ce_im
                float4 q2A=QLOAD(2,pqA,bA), q2B=QLOAD(2,pqB,bB);
                float4 q3A=QLOAD(3,pqA,bA), q3B=QLOAD(3,pqB,bB);
                float4 c0A=ELOAD(2,peA,eA), c0B=ELOAD(2,peB,eB);
                float4 c1A=ELOAD(3,peA,eA), c1B=ELOAD(3,peB,eB);
#pragma unroll
                for (int k = 0; k < 4; ++k) {
                    acc[1][0][0]=fmaf(COMP(q2A,k),COMP(c0A,k),fmaf(COMP(q3A,k),COMP(c1A,k),acc[1][0][0]));
                    acc[1][0][1]=fmaf(COMP(q2B,k),COMP(c0A,k),fmaf(COMP(q3B,k),COMP(c1A,k),acc[1][0][1]));
                    acc[1][1][0]=fmaf(COMP(q2A,k),COMP(c0B,k),fmaf(COMP(q3A,k),COMP(c1B,k),acc[1][1][0]));
                    acc[1][1][1]=fmaf(COMP(q2B,k),COMP(c0B,k),fmaf(COMP(q3B,k),COMP(c1B,k),acc[1][1][1]));
                }
            }
            { // kdg + distmult
                float4 q4A=QLOAD(4,pqA,bA), q4B=QLOAD(4,pqB,bB);
                float4 k0A=ELOAD(4,peA,eA), k0B=ELOAD(4,peB,eB);
                float4 q5A=QLOAD(5,pqA,bA), q5B=QLOAD(5,pqB,bB);
                float4 d0A=ELOAD(5,peA,eA), d0B=ELOAD(5,peB,eB);
#pragma unroll
                for (int k = 0; k < 4; ++k) {
                    acc[2][0][0]=fmaf(COMP(q4A,k),COMP(k0A,k),acc[2][0][0]);
                    acc[2][0][1]=fmaf(COMP(q4B,k),COMP(k0A,k),acc[2][0][1]);
                    acc[2][1][0]=fmaf(COMP(q4A,k),COMP(k0B,k),acc[2][1][0]);
                    acc[2][1][1]=fmaf(COMP(q4B,k),COMP(k0B,k),acc[2][1][1]);
                    acc[3][0][0]=fmaf(COMP(q5A,k),COMP(d0A,k),acc[3][0][0]);
                    acc[3][0][1]=fmaf(COMP(q5B,k),COMP(d0A,k),acc[3][0][1]);
                    acc[3][1][0]=fmaf(COMP(q5A,k),COMP(d0B,k),acc[3][1][0]);
                    acc[3][1][1]=fmaf(COMP(q5B,k),COMP(d0B,k),acc[3][1][1]);
                }
            }
            { // simple: q6·se_t + q7·se_h
                float4 q6A=QLOAD(6,pqA,bA), q6B=QLOAD(6,pqB,bB);
                float4 q7A=QLOAD(7,pqA,bA), q7B=QLOAD(7,pqB,bB);
                float4 s0A=ELOAD(6,peA,eA), s0B=ELOAD(6,peB,eB);
                float4 s1A=ELOAD(7,peA,eA), s1B=ELOAD(7,peB,eB);
#pragma unroll
                for (int k = 0; k < 4; ++k) {
                    acc[4][0][0]=fmaf(COMP(q6A,k),COMP(s0A,k),fmaf(COMP(q7A,k),COMP(s1A,k),acc[4][0][0]));
                    acc[4][0][1]=fmaf(COMP(q6B,k),COMP(s0A,k),fmaf(COMP(q7B,k),COMP(s1A,k),acc[4][0][1]));
                    acc[4][1][0]=fmaf(COMP(q6A,k),COMP(s0B,k),fmaf(COMP(q7A,k),COMP(s1B,k),acc[4][1][0]));
                    acc[4][1][1]=fmaf(COMP(q6B,k),COMP(s0B,k),fmaf(COMP(q7B,k),COMP(s1B,k),acc[4][1][1]));
                }
            }
        }
    }

    // ---- cross-ds (cross-wave) reduction via LDS overlay on ebuf ----
    __syncthreads();
    float* ov = &ebuf[0][0][0][0];   // 512 threads * 20 floats = 10240 <= 16384
    {
        int base = tid * 20;
#pragma unroll
        for (int m = 0; m < NM; ++m)
#pragma unroll
            for (int je = 0; je < 2; ++je)
#pragma unroll
                for (int jb = 0; jb < 2; ++jb)
                    ov[base + m*4 + je*2 + jb] = acc[m][je][jb];
    }
    __syncthreads();
    float4* red2 = (float4*)&qbuf[0][0][0][0];   // [4][40] overlay (640 floats)
    if (tid < 256) {
        int e_l = tid >> 3, b = tid & 7;
        int rg2 = e_l >> 1, je = e_l & 1, bg2 = b >> 1, jb = b & 1;
        float vals[NM];
#pragma unroll
        for (int m = 0; m < NM; ++m) {
            float s = 0.f;
#pragma unroll
            for (int d2 = 0; d2 < 8; ++d2)
                s += ov[(d2*64 + rg2*4 + bg2) * 20 + m*4 + je*2 + jb];
            vals[m] = s;
        }
        vals[0] = -vals[0];
        vals[4] = 0.5f * vals[4];
        int e = e0 + e_l;
#pragma unroll
        for (int m = 0; m < NM; ++m) S[(m*8 + b)*N_ENT + e] = vals[m];

        float mn[NM], mx[NM], sm[NM], sq[NM];
#pragma unroll
        for (int m = 0; m < NM; ++m) {
            mn[m] = vals[m]; mx[m] = vals[m]; sm[m] = vals[m]; sq[m] = vals[m]*vals[m];
        }
#pragma unroll
        for (int off = 8; off <= 32; off <<= 1) {   // reduce over e_l low bits (lane 3..5)
#pragma unroll
            for (int m = 0; m < NM; ++m) {
                mn[m] = fminf(mn[m], __shfl_xor(mn[m], off, 64));
                mx[m] = fmaxf(mx[m], __shfl_xor(mx[m], off, 64));
                sm[m] += __shfl_xor(sm[m], off, 64);
                sq[m] += __shfl_xor(sq[m], off, 64);
            }
        }
        if ((tid & 63) < 8) {   // lane b = tid&7; wave = e-octet tid>>6
#pragma unroll
            for (int m = 0; m < NM; ++m)
                red2[(tid >> 6)*40 + m*8 + b] = make_float4(mn[m], mx[m], sm[m], sq[m]);
        }
    }
    __syncthreads();
    if (tid < 40) {
        float4 o = red2[tid];
#pragma unroll
        for (int w = 1; w < 4; ++w) {
            float4 v = red2[w*40 + tid];
            o.x = fminf(o.x, v.x);
            o.y = fmaxf(o.y, v.y);
            o.z += v.z;
            o.w += v.w;
        }
        *(float4*)(part + (blockIdx.x*40 + tid)*4) = o;
    }
}

// ---------------- K_red: parallel reduction of 625 partials per (m,b) ----------------
__global__ __launch_bounds__(256) void k_red(float* __restrict__ ws)
{
    const float* part = ws + PART_OFF;
    const int p = blockIdx.x;      // 0..39 = m*8+b
    const int t = threadIdx.x;
    __shared__ float  smn[4], smx[4];
    __shared__ double ssm[4], ssq[4];

    float mn = INFINITY, mx = -INFINITY;
    double sm = 0.0, sq = 0.0;
    for (int blk = t; blk < NBLK_MAIN; blk += 256) {
        float4 v = LD4(part + (blk*40 + p)*4);
        mn = fminf(mn, v.x); mx = fmaxf(mx, v.y);
        sm += (double)v.z;   sq += (double)v.w;
    }
#pragma unroll
    for (int off = 1; off < 64; off <<= 1) {
        mn = fminf(mn, __shfl_xor(mn, off, 64));
        mx = fmaxf(mx, __shfl_xor(mx, off, 64));
        sm += __shfl_xor(sm, off, 64);
        sq += __shfl_xor(sq, off, 64);
    }
    if ((t & 63) == 0) {
        smn[t >> 6] = mn; smx[t >> 6] = mx; ssm[t >> 6] = sm; ssq[t >> 6] = sq;
    }
    __syncthreads();
    if (t == 0) {
        mn = fminf(fminf(smn[0], smn[1]), fminf(smn[2], smn[3]));
        mx = fmaxf(fmaxf(smx[0], smx[1]), fmaxf(smx[2], smx[3]));
        sm = ssm[0] + ssm[1] + ssm[2] + ssm[3];
        sq = ssq[0] + ssq[1] + ssq[2] + ssq[3];
        ws[MNMX_OFF + p*2]     = mn;
        ws[MNMX_OFF + p*2 + 1] = mx;
        double* sd = (double*)(ws + STATD_OFF);
        sd[p*2]     = sm;
        sd[p*2 + 1] = sq;
    }
}

// ---------------- K_mlp: features + 5-expert MLP + affine coefficients ----------------
__global__ __launch_bounds__(320) void k_mlp(
    const float* __restrict__ W0, const float* __restrict__ b0,
    const float* __restrict__ W1, const float* __restrict__ b1,
    const float* __restrict__ W2, const float* __restrict__ b2,
    const float* __restrict__ W3, const float* __restrict__ b3,
    float* __restrict__ ws)
{
    __shared__ float feat[NB][10];
    __shared__ float mnS[NM][NB], rngS[NM][NB];
    __shared__ float xA[NM][NB][64], xB[NM][NB][64];
    __shared__ float wS[NM][NB];

    int t = threadIdx.x;
    if (t < 40) {
        int m = t / 8, b = t % 8;
        float  mn = ws[MNMX_OFF + t*2];
        float  mx = ws[MNMX_OFF + t*2 + 1];
        const double* sd = (const double*)(ws + STATD_OFF);
        double sm = sd[t*2], sq = sd[t*2 + 1];
        float  rng  = mx - mn;
        double mean = sm / (double)N_ENT;
        float  md   = 1.0f - (float)((mean - (double)mn) / (double)rng);
        double va   = (sq - sm*sm/(double)N_ENT) / (double)(N_ENT - 1);
        float  vn   = (float)(va / ((double)rng * (double)rng));
        feat[b][2*m]   = md;
        feat[b][2*m+1] = vn;
        mnS[m][b] = mn; rngS[m][b] = rng;
    }
    __syncthreads();

    int ex = t / 64, o = t % 64;
    for (int b = 0; b < NB; ++b) {
        float a = b0[ex*64 + o];
#pragma unroll
        for (int i = 0; i < 10; ++i) a = fmaf(feat[b][i], W0[ex*640 + i*64 + o], a);
        xA[ex][b][o] = a;
    }
    __syncthreads();
    for (int b = 0; b < NB; ++b) {
        float a = b1[ex*64 + o];
        for (int i = 0; i < 64; ++i) a = fmaf(xA[ex][b][i], W1[ex*4096 + i*64 + o], a);
        xB[ex][b][o] = fmaxf(a, 0.f);
    }
    __syncthreads();
    for (int b = 0; b < NB; ++b) {
        float a = b2[ex*64 + o];
        for (int i = 0; i < 64; ++i) a = fmaf(xB[ex][b][i], W2[ex*4096 + i*64 + o], a);
        xA[ex][b][o] = fmaxf(a, 0.f);
    }
    __syncthreads();
    if (o == 0) {
        for (int b = 0; b < NB; ++b) {
            float a = b3[ex];
            for (int i = 0; i < 64; ++i) a = fmaf(xA[ex][b][i], W3[ex*64 + i], a);
            wS[ex][b] = fmaxf(a, 0.f);
        }
    }
    __syncthreads();
    if (t < 8) {
        int b = t;
        float wm = 0.f;
        for (int m = 0; m < NM; ++m) wm = fmaxf(wm, fabsf(wS[m][b]));
        float cst = 0.f;
        for (int m = 0; m < NM; ++m) {
            float w  = wS[m][b] / wm;
            float cc = w / rngS[m][b];
            ws[C_OFF + m*8 + b] = cc;
            cst -= cc * mnS[m][b];
        }
        ws[CONST_OFF + b] = cst;
    }
}

// ---------------- K_combine ----------------
__global__ __launch_bounds__(256) void k_comb(const float* __restrict__ ws,
                                              float* __restrict__ out)
{
    int t = blockIdx.x * 256 + threadIdx.x;
    if (t >= NB * (N_ENT/4)) return;
    int b = t / (N_ENT/4);
    int e = (t % (N_ENT/4)) * 4;
    const float* S = ws + S_OFF;
    float c0 = ws[C_OFF +  0 + b], c1 = ws[C_OFF +  8 + b], c2 = ws[C_OFF + 16 + b];
    float c3 = ws[C_OFF + 24 + b], c4 = ws[C_OFF + 32 + b];
    float cst = ws[CONST_OFF + b];
    float4 s0 = *(const float4*)(S + (0*8 + b)*N_ENT + e);
    float4 s1 = *(const float4*)(S + (1*8 + b)*N_ENT + e);
    float4 s2 = *(const float4*)(S + (2*8 + b)*N_ENT + e);
    float4 s3 = *(const float4*)(S + (3*8 + b)*N_ENT + e);
    float4 s4 = *(const float4*)(S + (4*8 + b)*N_ENT + e);
    float4 o4;
    o4.x = fmaf(c0,s0.x, fmaf(c1,s1.x, fmaf(c2,s2.x, fmaf(c3,s3.x, fmaf(c4,s4.x, cst)))));
    o4.y = fmaf(c0,s0.y, fmaf(c1,s1.y, fmaf(c2,s2.y, fmaf(c3,s3.y, fmaf(c4,s4.y, cst)))));
    o4.z = fmaf(c0,s0.z, fmaf(c1,s1.z, fmaf(c2,s2.z, fmaf(c3,s3.z, fmaf(c4,s4.z, cst)))));
    o4.w = fmaf(c0,s0.w, fmaf(c1,s1.w, fmaf(c2,s2.w, fmaf(c3,s3.w, fmaf(c4,s4.w, cst)))));
    *(float4*)(out + b*N_ENT + e) = o4;
}

extern "C" void kernel_launch(void* const* d_in, const int* in_sizes, int n_in,
                              void* d_out, int out_size, void* d_ws, size_t ws_size,
                              hipStream_t stream)
{
    const int*   batch  = (const int*)  d_in[0];
    const float* eemb   = (const float*)d_in[1];
    const float* remb   = (const float*)d_in[2];
    const float* ce_re  = (const float*)d_in[3];
    const float* ce_im  = (const float*)d_in[4];
    const float* cr_re  = (const float*)d_in[5];
    const float* cr_im  = (const float*)d_in[6];
    const float* de     = (const float*)d_in[7];
    const float* dr     = (const float*)d_in[8];
    const float* ke     = (const float*)d_in[9];
    const float* kr     = (const float*)d_in[10];
    const float* se_h   = (const float*)d_in[11];
    const float* se_t   = (const float*)d_in[12];
    const float* sr     = (const float*)d_in[13];
    const float* sr_inv = (const float*)d_in[14];
    const float* W0 = (const float*)d_in[15];
    const float* b0 = (const float*)d_in[16];
    const float* W1 = (const float*)d_in[17];
    const float* b1 = (const float*)d_in[18];
    const float* W2 = (const float*)d_in[19];
    const float* b2 = (const float*)d_in[20];
    const float* W3 = (const float*)d_in[21];
    const float* b3 = (const float*)d_in[22];
    float* ws  = (float*)d_ws;
    float* out = (float*)d_out;

    k_q    <<<8, 256, 0, stream>>>(batch, eemb, remb, ce_re, ce_im, cr_re, cr_im,
                                   de, dr, ke, kr, se_h, se_t, sr, sr_inv, ws);
    k_main <<<NBLK_MAIN, 512, 0, stream>>>(eemb, ce_re, ce_im, ke, de, se_h, se_t, ws);
    k_red  <<<40, 256, 0, stream>>>(ws);
    k_mlp  <<<1, 320, 0, stream>>>(W0, b0, W1, b1, W2, b2, W3, b3, ws);
    k_comb <<<(NB*(N_ENT/4) + 255)/256, 256, 0, stream>>>(ws, out);
}